// Round 12
// baseline (109.361 us; speedup 1.0000x reference)
//
#include <hip/hip_runtime.h>

typedef __attribute__((ext_vector_type(8))) short s16x8;
typedef __attribute__((ext_vector_type(4))) float f32x4;
typedef __attribute__((ext_vector_type(4))) unsigned int u32x4;
typedef __attribute__((ext_vector_type(2))) unsigned int u32x2;
typedef unsigned short u16;
typedef unsigned int u32;
typedef unsigned long long u64;

__device__ __forceinline__ u16 f2bf(float f) {
  u32 u = __float_as_uint(f);
  u32 r = u + 0x7fffu + ((u >> 16) & 1u);
  return (u16)(r >> 16);
}
__device__ __forceinline__ float bf2f(u16 h) {
  return __uint_as_float(((u32)h) << 16);
}

typedef __attribute__((address_space(3))) char lds_char_t;
typedef __attribute__((address_space(1))) const char glb_char_t;
__device__ __forceinline__ void gl2lds16(const void* g, void* l) {
  __builtin_amdgcn_global_load_lds((glb_char_t*)g, (lds_char_t*)l, 16, 0, 0);
}

#define HS_N 3145728   // 4096*768
#define W_N  589824    // 768*768
#define LOG2E 1.44269504f

// ---------------- K0: f32 -> bf16 conversions + bias concat ----------------
__global__ __launch_bounds__(256) void convert_kernel(
    const float* __restrict__ hs, const float* __restrict__ wq, const float* __restrict__ wk,
    const float* __restrict__ wv, const float* __restrict__ wo,
    const float* __restrict__ bq, const float* __restrict__ bk, const float* __restrict__ bv,
    u16* __restrict__ hsb, u16* __restrict__ wqkvb, u16* __restrict__ wob,
    float* __restrict__ biasqkv)
{
  int t = blockIdx.x * 256 + threadIdx.x;
  long i = (long)t * 8;
  const float* src;
  u16* dst;
  if (i < HS_N)              { src = hs + i;                  dst = hsb + i; }
  else if (i < HS_N + W_N)   { src = wq + (i - HS_N);         dst = wqkvb + (i - HS_N); }
  else if (i < HS_N + 2*W_N) { src = wk + (i - HS_N - W_N);   dst = wqkvb + (i - HS_N); }
  else if (i < HS_N + 3*W_N) { src = wv + (i - HS_N - 2*W_N); dst = wqkvb + (i - HS_N); }
  else                       { src = wo + (i - HS_N - 3*W_N); dst = wob + (i - HS_N - 3*W_N); }
  float4 a = ((const float4*)src)[0];
  float4 b = ((const float4*)src)[1];
  uint4 o;
  o.x = (u32)f2bf(a.x) | ((u32)f2bf(a.y) << 16);
  o.y = (u32)f2bf(a.z) | ((u32)f2bf(a.w) << 16);
  o.z = (u32)f2bf(b.x) | ((u32)f2bf(b.y) << 16);
  o.w = (u32)f2bf(b.z) | ((u32)f2bf(b.w) << 16);
  *(uint4*)dst = o;
  if (t < 2304) biasqkv[t] = (t < 768) ? bq[t] : ((t < 1536) ? bk[t - 768] : bv[t - 1536]);
}

// ---------------- GEMM v3: R4 pipeline + FUSED qk_ext epilogue ----------------
// MODE 0: QKV proj. Q/K tiles: compute qA projection + norms in epilogue, write
//         qAe/kAe (128-col rows, LOG2E-folded scales) + beta2 directly (qk_ext fused).
//         V tiles: LDS-transpose -> V^T[bh][d][s] (unchanged).
// MODE 1: f32 output [M][768].
template<int MODE>
__global__ __launch_bounds__(256, 2) void gemm_bt(
    const u16* __restrict__ A, const u16* __restrict__ Bt, const float* __restrict__ bias,
    float* __restrict__ outF, u16* __restrict__ Vtb, const float* __restrict__ Am,
    const float* __restrict__ maskp, u16* __restrict__ qAe, u16* __restrict__ kAe,
    float* __restrict__ beta2)
{
  constexpr int NT = (MODE == 0) ? 18 : 6;
  constexpr int CPX = NT * 64 / 8;

  __shared__ __align__(16) char sm[73728];
  char* const smA = sm;
  char* const smB = sm + 24576;

  const int tid = threadIdx.x;
  const int lane = tid & 63;
  const int w = tid >> 6;
  const int l15 = lane & 15, g = lane >> 4;
  const int wid = (blockIdx.x & 7) * CPX + (blockIdx.x >> 3);
  const int bx = wid % NT, by = wid / NT;
  const int mBase = by * 64;
  const int nBase = bx * 128;
  const int wr = w >> 1, wc = w & 1;
  const int mW = wr * 32, nW = wc * 64;

  f32x4 zero = {0.f, 0.f, 0.f, 0.f};
  f32x4 acc[2][4];
  #pragma unroll
  for (int i = 0; i < 2; i++)
    #pragma unroll
    for (int j = 0; j < 4; j++) acc[i][j] = zero;

  const u16* Arow = A + (long)mBase * 768;
  const u16* Brow = Bt + (long)nBase * 768;

  auto stage = [&](int c, int kb) {
    const int k0 = c * 64;
    #pragma unroll
    for (int i = 0; i < 2; i++) {
      int o = (i * 256 + tid) * 16;
      int r = o >> 7;
      int sl = ((o >> 4) & 7) ^ (r & 7);
      gl2lds16(Arow + (long)r * 768 + k0 + sl * 8,
               smA + kb * 8192 + i * 4096 + w * 1024);
    }
    #pragma unroll
    for (int i = 0; i < 4; i++) {
      int o = (i * 256 + tid) * 16;
      int r = o >> 7;
      int sl = ((o >> 4) & 7) ^ (r & 7);
      gl2lds16(Brow + (long)r * 768 + k0 + sl * 8,
               smB + kb * 16384 + i * 4096 + w * 1024);
    }
  };

  auto compute = [&](int kb) {
    const char* bufA = smA + kb * 8192;
    const char* bufB = smB + kb * 16384;
    #pragma unroll
    for (int kh = 0; kh < 2; kh++) {
      s16x8 af[2], bf[4];
      #pragma unroll
      for (int mi = 0; mi < 2; mi++) {
        int R = mW + mi * 16 + l15;
        af[mi] = *(const s16x8*)(bufA + R * 128 + (((kh * 4 + g) ^ (l15 & 7)) << 4));
      }
      #pragma unroll
      for (int ni = 0; ni < 4; ni++) {
        int R = nW + ni * 16 + l15;
        bf[ni] = *(const s16x8*)(bufB + R * 128 + (((kh * 4 + g) ^ (l15 & 7)) << 4));
      }
      #pragma unroll
      for (int mi = 0; mi < 2; mi++)
        #pragma unroll
        for (int ni = 0; ni < 4; ni++)
          acc[mi][ni] = __builtin_amdgcn_mfma_f32_16x16x32_bf16(af[mi], bf[ni], acc[mi][ni], 0, 0, 0);
    }
  };

  auto body = [&](int c, int kb, int kbn) {
    if (c < 11) { stage(c + 1, kbn); asm volatile("s_waitcnt vmcnt(6)" ::: "memory"); }
    else        { asm volatile("s_waitcnt vmcnt(0)" ::: "memory"); }
    asm volatile("s_barrier" ::: "memory");
    compute(kb);
  };

  stage(0, 0);
  #pragma unroll 1
  for (int cc = 0; cc < 4; cc++) {
    body(cc * 3,     0, 1);
    body(cc * 3 + 1, 1, 2);
    body(cc * 3 + 2, 2, 0);
  }
  __syncthreads();

  const int b_ = mBase >> 10;
  const int s0b = mBase & 1023;

  if constexpr (MODE == 1) {
    #pragma unroll
    for (int mi = 0; mi < 2; mi++)
      #pragma unroll
      for (int ni = 0; ni < 4; ni++) {
        int n = nBase + nW + ni * 16 + l15;
        int m0 = mBase + mW + mi * 16 + g * 4;
        float bb = bias[n];
        outF[(long)m0 * 768 + n]       = acc[mi][ni][0] + bb;
        outF[(long)(m0 + 1) * 768 + n] = acc[mi][ni][1] + bb;
        outF[(long)(m0 + 2) * 768 + n] = acc[mi][ni][2] + bb;
        outF[(long)(m0 + 3) * 768 + n] = acc[mi][ni][3] + bb;
      }
  } else {
    const int typ = bx / 6;                     // 0=Q, 1=K, 2=V (tile-uniform)
    if (typ == 2) {
      // V: stage C^T then write V^T[bh][d][s] in 64B runs (unchanged from R4)
      u16* ct = (u16*)sm;
      #pragma unroll
      for (int mi = 0; mi < 2; mi++)
        #pragma unroll
        for (int ni = 0; ni < 4; ni++) {
          int nr = nW + ni * 16 + l15;
          int mr = mW + mi * 16 + g * 4;
          float bb = bias[nBase + nr];
          u32 lo = (u32)f2bf(acc[mi][ni][0] + bb) | ((u32)f2bf(acc[mi][ni][1] + bb) << 16);
          u32 hi = (u32)f2bf(acc[mi][ni][2] + bb) | ((u32)f2bf(acc[mi][ni][3] + bb) << 16);
          *(u64*)(ct + nr * 72 + mr) = (u64)lo | ((u64)hi << 32);
        }
      __syncthreads();
      int dr = tid >> 1, part = tid & 1;
      int hn = (bx - 12) * 128 + dr;
      int h = hn >> 6, d = hn & 63;
      long bh = (long)b_ * 12 + h;
      u16* dst = Vtb + (bh << 16) + (d << 10) + s0b + part * 32;
      const u16* srl = ct + dr * 72 + part * 32;
      #pragma unroll
      for (int i = 0; i < 4; i++)
        *(uint4*)(dst + i * 8) = *(const uint4*)(srl + i * 8);
    } else {
      // Q/K: FUSED qk_ext. Stage C rows [64][130] u16 (stride 130: +1 bank/row),
      // then 2 threads per (s,head)-row compute the rank-16 projection + norms.
      u16* cl = (u16*)sm;
      #pragma unroll
      for (int mi = 0; mi < 2; mi++)
        #pragma unroll
        for (int ni = 0; ni < 4; ni++) {
          int nr = nW + ni * 16 + l15;
          int mr = mW + mi * 16 + g * 4;
          float bb = bias[nBase + nr];
          cl[(mr + 0) * 130 + nr] = f2bf(acc[mi][ni][0] + bb);
          cl[(mr + 1) * 130 + nr] = f2bf(acc[mi][ni][1] + bb);
          cl[(mr + 2) * 130 + nr] = f2bf(acc[mi][ni][2] + bb);
          cl[(mr + 3) * 130 + nr] = f2bf(acc[mi][ni][3] + bb);
        }
      __syncthreads();
      const bool isK = (typ == 1);
      const int rowid = tid >> 1, dh = tid & 1;
      const int sl = rowid & 63, hh = rowid >> 6;
      const u16* crow = cl + sl * 130 + hh * 64 + dh * 32;
      const int h = (bx - typ * 6) * 2 + hh;
      const float* Ah = Am + h * 1024 + dh * 512;
      float qa[16];
      #pragma unroll
      for (int r = 0; r < 16; r++) qa[r] = 0.f;
      float s2 = 0.f;
      #pragma unroll
      for (int dd = 0; dd < 32; dd++) {
        float qd = bf2f(crow[dd]);
        s2 += qd * qd;
        #pragma unroll
        for (int r = 0; r < 16; r++) qa[r] += qd * Ah[dd * 16 + r];
      }
      #pragma unroll
      for (int r = 0; r < 16; r++) qa[r] += __shfl_xor(qa[r], 1);
      s2 += __shfl_xor(s2, 1);
      const float sA_ = isK ? 1.0f : 0.25f * LOG2E;
      const float sQ_ = isK ? 1e-3f : 0.25e-3f * LOG2E;
      const int s0 = s0b + sl;
      const long bhq = (long)b_ * 12 + h;
      u16* dst = (isK ? kAe : qAe) + (((bhq << 10) + s0) << 7);
      uint4 z = {0, 0, 0, 0};
      if (dh == 0) {
        union { u16 us[48]; uint4 v4[6]; } ob;
        #pragma unroll
        for (int r = 0; r < 16; r++) ob.us[r] = f2bf(qa[r] * sA_);
        #pragma unroll
        for (int dd = 0; dd < 32; dd++) ob.us[16 + dd] = f2bf(bf2f(crow[dd]) * sQ_);
        #pragma unroll
        for (int i = 0; i < 6; i++) ((uint4*)dst)[i] = ob.v4[i];
        ((uint4*)dst)[10] = z; ((uint4*)dst)[11] = z; ((uint4*)dst)[12] = z;
        if (isK) {
          float kk = 1e-6f * s2;
          #pragma unroll
          for (int r = 0; r < 16; r++) kk += qa[r] * qa[r];
          beta2[(bhq << 10) + s0] = LOG2E * (-0.125f * kk + maskp[(b_ << 10) + s0]);
        }
      } else {
        union { u16 us[32]; uint4 v4[4]; } ob;
        #pragma unroll
        for (int dd = 0; dd < 32; dd++) ob.us[dd] = f2bf(bf2f(crow[dd]) * sQ_);
        #pragma unroll
        for (int i = 0; i < 4; i++) ((uint4*)dst)[6 + i] = ob.v4[i];
        ((uint4*)dst)[13] = z; ((uint4*)dst)[14] = z; ((uint4*)dst)[15] = z;
      }
    }
  }
}

// ---------------- K3: attention (R10-exact, best measured) ----------------
// grid 768 = 48 bh x 16 qtiles(64 rows), XCD-swizzled; block 128 = 2 waves,
// wave owns 32 q rows. 16 iterations of 64 t each.
__global__ __launch_bounds__(128, 2) void attn_kernel(
    const u16* __restrict__ qAe, const u16* __restrict__ kAe, const u16* __restrict__ Vtb,
    const float* __restrict__ beta2, u16* __restrict__ ctxb)
{
  const int tid = threadIdx.x;
  const int lane = tid & 63;
  const int w = tid >> 6;
  const int l15 = lane & 15, g = lane >> 4;
  const int wid = ((int)blockIdx.x & 7) * 96 + ((int)blockIdx.x >> 3);  // 768 = 8*96
  const int bh = wid >> 4;
  const int qt = wid & 15;
  const int q0 = qt * 64 + w * 32;

  // LDS: K dbuf 2x16384 | P 2 waves x 4608 (32 rows x 128B, stride 144) | beta 4096
  __shared__ __align__(16) char sm[46080];
  char* const kb0  = sm;
  char* const kb1  = sm + 16384;
  char* const Pw   = sm + 32768 + w * 4608;
  float* const Blds = (float*)(sm + 41984);

  const u16* qbase = qAe + ((long)(bh * 1024 + q0) << 7);
  const u16* kbase = kAe + ((long)bh << 17);
  const u16* vbase = Vtb + ((long)bh << 16);
  const float* betab = beta2 + (bh << 10);

  // prologue FIFO: [bqv 6][beta 4][K0 8] = 18
  u32x4 bqv[2][3];
  #pragma unroll
  for (int qf = 0; qf < 2; qf++)
    #pragma unroll
    for (int ks = 0; ks < 3; ks++) {
      const u16* a = qbase + ((qf * 16 + l15) << 7) + ks * 32 + g * 8;
      asm volatile("global_load_dwordx4 %0, %1, off" : "=v"(bqv[qf][ks]) : "v"(a));
    }
  #pragma unroll
  for (int i = 0; i < 4; i++)
    gl2lds16(betab + i * 256 + lane * 4, (char*)Blds + i * 1024);   // 1024B/instr

  auto stageK = [&](int c, char* buf) {
    const int t0 = c * 64;
    #pragma unroll
    for (int i2 = 0; i2 < 8; i2++) {
      int i = w * 8 + i2;
      int r = i * 4 + (lane >> 4);
      int col = ((lane & 15) ^ (r & 7)) * 8;          // pre-swizzled source (rule #21)
      gl2lds16(kbase + (long)(t0 + r) * 128 + col, buf + i * 1024);
    }
  };
  auto loadV = [&](int c, u32x4 (&dst)[8]) {
    const int t0 = c * 64;
    #pragma unroll
    for (int ks2 = 0; ks2 < 2; ks2++)
      #pragma unroll
      for (int df = 0; df < 4; df++) {
        const u16* a = vbase + ((df * 16 + l15) << 10) + t0 + ks2 * 32 + g * 8;
        asm volatile("global_load_dwordx4 %0, %1, off" : "=v"(dst[ks2 * 4 + df]) : "v"(a));
      }
  };

  f32x4 zero = {0.f, 0.f, 0.f, 0.f};
  f32x4 cacc[2][4];
  #pragma unroll
  for (int a = 0; a < 2; a++)
    #pragma unroll
    for (int b = 0; b < 4; b++) cacc[a][b] = zero;
  float rsum[2] = {0.f, 0.f};
  u32x4 vb[8];

  stageK(0, kb0);

  std::integral_constant<bool, false> Ff;
  std::integral_constant<bool, true>  Tt;

  auto iter = [&](auto LASTC, int c, const char* bufc, char* bufn) {
    constexpr bool LAST = decltype(LASTC)::value;
    loadV(c, vb);                                   // +8
    asm volatile("s_waitcnt vmcnt(8)" ::: "memory"); // K(c) landed (V(c) remains)
    asm volatile("s_barrier" ::: "memory");
    __builtin_amdgcn_sched_barrier(0);
    if constexpr (!LAST) stageK(c + 1, bufn);       // post-barrier: WAR-safe slot
    // phase A: S^T = K @ Q^T (24 MFMA, 12 ds_read_b128 swizzled)
    f32x4 sacc[4][2];
    #pragma unroll
    for (int tf = 0; tf < 4; tf++) { sacc[tf][0] = zero; sacc[tf][1] = zero; }
    #pragma unroll
    for (int tf = 0; tf < 4; tf++)
      #pragma unroll
      for (int ks = 0; ks < 3; ks++) {
        s16x8 ak = *(const s16x8*)(bufc + (tf * 16 + l15) * 256 +
                                   ((ks * 64 + g * 16) ^ ((l15 & 7) << 4)));
        s16x8 b0 = __builtin_bit_cast(s16x8, bqv[0][ks]);
        s16x8 b1 = __builtin_bit_cast(s16x8, bqv[1][ks]);
        sacc[tf][0] = __builtin_amdgcn_mfma_f32_16x16x32_bf16(ak, b0, sacc[tf][0], 0, 0, 0);
        sacc[tf][1] = __builtin_amdgcn_mfma_f32_16x16x32_bf16(ak, b1, sacc[tf][1], 0, 0, 0);
      }
    if constexpr (!LAST) asm volatile("s_waitcnt vmcnt(8)" ::: "memory");  // V(c) landed
    else                 asm volatile("s_waitcnt vmcnt(0)" ::: "memory");
    __builtin_amdgcn_sched_barrier(0);              // rule #18
    // softmax: P = 2^(S + beta) -> bf16 -> per-wave LDS [q][t], stride 144
    #pragma unroll
    for (int tf = 0; tf < 4; tf++) {
      f32x4 bb = *(const f32x4*)((const char*)Blds + c * 256 + tf * 64 + g * 16);
      #pragma unroll
      for (int qf = 0; qf < 2; qf++) {
        float e0, e1, e2, e3;
        asm("v_exp_f32 %0, %1" : "=v"(e0) : "v"(sacc[tf][qf][0] + bb[0]));
        asm("v_exp_f32 %0, %1" : "=v"(e1) : "v"(sacc[tf][qf][1] + bb[1]));
        asm("v_exp_f32 %0, %1" : "=v"(e2) : "v"(sacc[tf][qf][2] + bb[2]));
        asm("v_exp_f32 %0, %1" : "=v"(e3) : "v"(sacc[tf][qf][3] + bb[3]));
        rsum[qf] += (e0 + e1) + (e2 + e3);
        u32 p01, p23;
        asm("v_cvt_pk_bf16_f32 %0, %1, %2" : "=v"(p01) : "v"(e0), "v"(e1));
        asm("v_cvt_pk_bf16_f32 %0, %1, %2" : "=v"(p23) : "v"(e2), "v"(e3));
        u32x2 pk = {p01, p23};
        *(u32x2*)(Pw + (qf * 16 + l15) * 144 + tf * 32 + g * 8) = pk;
      }
    }
    // phase B: ctx += P @ V (16 MFMA; P from own-wave LDS, V in regs)
    #pragma unroll
    for (int qf = 0; qf < 2; qf++)
      #pragma unroll
      for (int ks2 = 0; ks2 < 2; ks2++) {
        s16x8 ap = *(const s16x8*)(Pw + (qf * 16 + l15) * 144 + ks2 * 64 + g * 16);
        #pragma unroll
        for (int df = 0; df < 4; df++) {
          s16x8 bv = __builtin_bit_cast(s16x8, vb[ks2 * 4 + df]);
          cacc[qf][df] = __builtin_amdgcn_mfma_f32_16x16x32_bf16(ap, bv, cacc[qf][df], 0, 0, 0);
        }
      }
  };

  #pragma unroll 1
  for (int c2 = 0; c2 < 7; c2++) {
    iter(Ff, 2 * c2,     kb0, kb1);
    iter(Ff, 2 * c2 + 1, kb1, kb0);
  }
  iter(Ff, 14, kb0, kb1);
  iter(Tt, 15, kb1, kb0);

  // epilogue: per-wave softmax normalize + write
  #pragma unroll
  for (int qf = 0; qf < 2; qf++) {
    rsum[qf] += __shfl_xor(rsum[qf], 16);
    rsum[qf] += __shfl_xor(rsum[qf], 32);
  }
  const int b_ = bh / 12, h = bh % 12;
  #pragma unroll
  for (int qf = 0; qf < 2; qf++) {
    #pragma unroll
    for (int j = 0; j < 4; j++) {
      float rs = __shfl(rsum[qf], g * 4 + j);
      float rinv = 1.0f / rs;
      int qg = q0 + qf * 16 + g * 4 + j;
      long base = ((long)(b_ * 1024 + qg)) * 768 + h * 64;
      #pragma unroll
      for (int df = 0; df < 4; df++)
        ctxb[base + df * 16 + l15] = f2bf(cacc[qf][df][j] * rinv);
    }
  }
}

// ---------------- launcher ----------------
extern "C" void kernel_launch(void* const* d_in, const int* in_sizes, int n_in,
                              void* d_out, int out_size, void* d_ws, size_t ws_size,
                              hipStream_t stream)
{
  (void)in_sizes; (void)n_in; (void)out_size; (void)ws_size;
  const float* hs   = (const float*)d_in[0];
  const float* mask = (const float*)d_in[1];
  const float* Wq   = (const float*)d_in[2];
  const float* bq   = (const float*)d_in[3];
  const float* Wk   = (const float*)d_in[4];
  const float* bk   = (const float*)d_in[5];
  const float* Wv   = (const float*)d_in[6];
  const float* bv   = (const float*)d_in[7];
  const float* Wo   = (const float*)d_in[8];
  const float* bo   = (const float*)d_in[9];
  const float* Am   = (const float*)d_in[10];
  float* out = (float*)d_out;

  char* p = (char*)d_ws;
  u16* hsb      = (u16*)p;   p += 6291456;
  u16* wqkvb    = (u16*)p;   p += 3538944;
  u16* wob      = (u16*)p;   p += 1179648;
  float* biasqkv= (float*)p; p += 9216;
  u16* Vtb      = (u16*)p;   p += 6291456;
  u16* qAeb     = (u16*)p;   p += 12582912;
  u16* kAeb     = (u16*)p;   p += 12582912;
  float* beta2  = (float*)p; p += 196608;
  u16* ctxb     = (u16*)p;   p += 6291456;

  convert_kernel<<<2688, 256, 0, stream>>>(hs, Wq, Wk, Wv, Wo, bq, bk, bv,
                                           hsb, wqkvb, wob, biasqkv);
  gemm_bt<0><<<1152, 256, 0, stream>>>(hsb, wqkvb, biasqkv, nullptr,
                                       Vtb, Am, mask, qAeb, kAeb, beta2);
  attn_kernel<<<768, 128, 0, stream>>>(qAeb, kAeb, Vtb, beta2, ctxb);
  gemm_bt<1><<<384, 256, 0, stream>>>(ctxb, wob, bo, out,
                                      nullptr, nullptr, nullptr, nullptr, nullptr, nullptr);
}

// Round 13
// 107.571 us; speedup vs baseline: 1.0166x; 1.0166x over previous
//
#include <hip/hip_runtime.h>

typedef __attribute__((ext_vector_type(8))) short s16x8;
typedef __attribute__((ext_vector_type(4))) float f32x4;
typedef __attribute__((ext_vector_type(4))) unsigned int u32x4;
typedef __attribute__((ext_vector_type(2))) unsigned int u32x2;
typedef unsigned short u16;
typedef unsigned int u32;
typedef unsigned long long u64;

__device__ __forceinline__ u16 f2bf(float f) {
  u32 u = __float_as_uint(f);
  u32 r = u + 0x7fffu + ((u >> 16) & 1u);
  return (u16)(r >> 16);
}
__device__ __forceinline__ float bf2f(u16 h) {
  return __uint_as_float(((u32)h) << 16);
}

typedef __attribute__((address_space(3))) char lds_char_t;
typedef __attribute__((address_space(1))) const char glb_char_t;
__device__ __forceinline__ void gl2lds16(const void* g, void* l) {
  __builtin_amdgcn_global_load_lds((glb_char_t*)g, (lds_char_t*)l, 16, 0, 0);
}

#define HS_N 3145728   // 4096*768
#define W_N  589824    // 768*768
#define LOG2E 1.44269504f

// ---------------- K0: f32 -> bf16 conversions + bias concat ----------------
__global__ __launch_bounds__(256) void convert_kernel(
    const float* __restrict__ hs, const float* __restrict__ wq, const float* __restrict__ wk,
    const float* __restrict__ wv, const float* __restrict__ wo,
    const float* __restrict__ bq, const float* __restrict__ bk, const float* __restrict__ bv,
    u16* __restrict__ hsb, u16* __restrict__ wqkvb, u16* __restrict__ wob,
    float* __restrict__ biasqkv)
{
  int t = blockIdx.x * 256 + threadIdx.x;
  long i = (long)t * 8;
  const float* src;
  u16* dst;
  if (i < HS_N)              { src = hs + i;                  dst = hsb + i; }
  else if (i < HS_N + W_N)   { src = wq + (i - HS_N);         dst = wqkvb + (i - HS_N); }
  else if (i < HS_N + 2*W_N) { src = wk + (i - HS_N - W_N);   dst = wqkvb + (i - HS_N); }
  else if (i < HS_N + 3*W_N) { src = wv + (i - HS_N - 2*W_N); dst = wqkvb + (i - HS_N); }
  else                       { src = wo + (i - HS_N - 3*W_N); dst = wob + (i - HS_N - 3*W_N); }
  float4 a = ((const float4*)src)[0];
  float4 b = ((const float4*)src)[1];
  uint4 o;
  o.x = (u32)f2bf(a.x) | ((u32)f2bf(a.y) << 16);
  o.y = (u32)f2bf(a.z) | ((u32)f2bf(a.w) << 16);
  o.z = (u32)f2bf(b.x) | ((u32)f2bf(b.y) << 16);
  o.w = (u32)f2bf(b.z) | ((u32)f2bf(b.w) << 16);
  *(uint4*)dst = o;
  if (t < 2304) biasqkv[t] = (t < 768) ? bq[t] : ((t < 1536) ? bk[t - 768] : bv[t - 1536]);
}

// ---------------- GEMM v2 (R4-exact): async-pipelined, C = A @ Bt^T + bias ----
template<int MODE>
__global__ __launch_bounds__(256, 2) void gemm_bt(
    const u16* __restrict__ A, const u16* __restrict__ Bt, const float* __restrict__ bias,
    float* __restrict__ outF, u16* __restrict__ Qb, u16* __restrict__ Kb, u16* __restrict__ Vtb)
{
  constexpr int NT = (MODE == 0) ? 18 : 6;
  constexpr int CPX = NT * 64 / 8;

  __shared__ __align__(16) char sm[73728];
  char* const smA = sm;
  char* const smB = sm + 24576;

  const int tid = threadIdx.x;
  const int lane = tid & 63;
  const int w = tid >> 6;
  const int l15 = lane & 15, g = lane >> 4;
  const int wid = (blockIdx.x & 7) * CPX + (blockIdx.x >> 3);
  const int bx = wid % NT, by = wid / NT;
  const int mBase = by * 64;
  const int nBase = bx * 128;
  const int wr = w >> 1, wc = w & 1;
  const int mW = wr * 32, nW = wc * 64;

  f32x4 zero = {0.f, 0.f, 0.f, 0.f};
  f32x4 acc[2][4];
  #pragma unroll
  for (int i = 0; i < 2; i++)
    #pragma unroll
    for (int j = 0; j < 4; j++) acc[i][j] = zero;

  const u16* Arow = A + (long)mBase * 768;
  const u16* Brow = Bt + (long)nBase * 768;

  auto stage = [&](int c, int kb) {
    const int k0 = c * 64;
    #pragma unroll
    for (int i = 0; i < 2; i++) {
      int o = (i * 256 + tid) * 16;
      int r = o >> 7;
      int sl = ((o >> 4) & 7) ^ (r & 7);
      gl2lds16(Arow + (long)r * 768 + k0 + sl * 8,
               smA + kb * 8192 + i * 4096 + w * 1024);
    }
    #pragma unroll
    for (int i = 0; i < 4; i++) {
      int o = (i * 256 + tid) * 16;
      int r = o >> 7;
      int sl = ((o >> 4) & 7) ^ (r & 7);
      gl2lds16(Brow + (long)r * 768 + k0 + sl * 8,
               smB + kb * 16384 + i * 4096 + w * 1024);
    }
  };

  auto compute = [&](int kb) {
    const char* bufA = smA + kb * 8192;
    const char* bufB = smB + kb * 16384;
    #pragma unroll
    for (int kh = 0; kh < 2; kh++) {
      s16x8 af[2], bf[4];
      #pragma unroll
      for (int mi = 0; mi < 2; mi++) {
        int R = mW + mi * 16 + l15;
        af[mi] = *(const s16x8*)(bufA + R * 128 + (((kh * 4 + g) ^ (l15 & 7)) << 4));
      }
      #pragma unroll
      for (int ni = 0; ni < 4; ni++) {
        int R = nW + ni * 16 + l15;
        bf[ni] = *(const s16x8*)(bufB + R * 128 + (((kh * 4 + g) ^ (l15 & 7)) << 4));
      }
      #pragma unroll
      for (int mi = 0; mi < 2; mi++)
        #pragma unroll
        for (int ni = 0; ni < 4; ni++)
          acc[mi][ni] = __builtin_amdgcn_mfma_f32_16x16x32_bf16(af[mi], bf[ni], acc[mi][ni], 0, 0, 0);
    }
  };

  auto body = [&](int c, int kb, int kbn) {
    if (c < 11) { stage(c + 1, kbn); asm volatile("s_waitcnt vmcnt(6)" ::: "memory"); }
    else        { asm volatile("s_waitcnt vmcnt(0)" ::: "memory"); }
    asm volatile("s_barrier" ::: "memory");
    compute(kb);
  };

  stage(0, 0);
  #pragma unroll 1
  for (int cc = 0; cc < 4; cc++) {
    body(cc * 3,     0, 1);
    body(cc * 3 + 1, 1, 2);
    body(cc * 3 + 2, 2, 0);
  }
  __syncthreads();

  const int b_ = mBase >> 10;
  const int s0b = mBase & 1023;

  if constexpr (MODE == 1) {
    #pragma unroll
    for (int mi = 0; mi < 2; mi++)
      #pragma unroll
      for (int ni = 0; ni < 4; ni++) {
        int n = nBase + nW + ni * 16 + l15;
        int m0 = mBase + mW + mi * 16 + g * 4;
        float bb = bias[n];
        outF[(long)m0 * 768 + n]       = acc[mi][ni][0] + bb;
        outF[(long)(m0 + 1) * 768 + n] = acc[mi][ni][1] + bb;
        outF[(long)(m0 + 2) * 768 + n] = acc[mi][ni][2] + bb;
        outF[(long)(m0 + 3) * 768 + n] = acc[mi][ni][3] + bb;
      }
  } else {
    const int typ = bx / 6;
    if (typ < 2) {
      u16* qk = (typ == 0) ? Qb : Kb;
      #pragma unroll
      for (int mi = 0; mi < 2; mi++)
        #pragma unroll
        for (int ni = 0; ni < 4; ni++) {
          int n = nBase + nW + ni * 16 + l15;
          int hn = n - typ * 768;
          int h = hn >> 6, d = hn & 63;
          long bh = (long)b_ * 12 + h;
          int s0 = s0b + mW + mi * 16 + g * 4;
          float bb = bias[n];
          u16* dst = qk + (bh << 16) + ((long)s0 << 6) + d;
          dst[0]   = f2bf(acc[mi][ni][0] + bb);
          dst[64]  = f2bf(acc[mi][ni][1] + bb);
          dst[128] = f2bf(acc[mi][ni][2] + bb);
          dst[192] = f2bf(acc[mi][ni][3] + bb);
        }
    } else {
      u16* ct = (u16*)sm;
      #pragma unroll
      for (int mi = 0; mi < 2; mi++)
        #pragma unroll
        for (int ni = 0; ni < 4; ni++) {
          int nr = nW + ni * 16 + l15;
          int mr = mW + mi * 16 + g * 4;
          float bb = bias[nBase + nr];
          u32 lo = (u32)f2bf(acc[mi][ni][0] + bb) | ((u32)f2bf(acc[mi][ni][1] + bb) << 16);
          u32 hi = (u32)f2bf(acc[mi][ni][2] + bb) | ((u32)f2bf(acc[mi][ni][3] + bb) << 16);
          *(u64*)(ct + nr * 72 + mr) = (u64)lo | ((u64)hi << 32);
        }
      __syncthreads();
      int dr = tid >> 1, part = tid & 1;
      int hn = (bx - 12) * 128 + dr;
      int h = hn >> 6, d = hn & 63;
      long bh = (long)b_ * 12 + h;
      u16* dst = Vtb + (bh << 16) + (d << 10) + s0b + part * 32;
      const u16* srl = ct + dr * 72 + part * 32;
      #pragma unroll
      for (int i = 0; i < 4; i++)
        *(uint4*)(dst + i * 8) = *(const uint4*)(srl + i * 8);
    }
  }
}

// ---------------- K2: extended features + beta, LOG2E folded; Ah staged in LDS -------
__global__ __launch_bounds__(256) void qk_ext_kernel(
    const u16* __restrict__ Qb, const u16* __restrict__ Kb, const float* __restrict__ Am,
    const float* __restrict__ mask, u16* __restrict__ qAe, u16* __restrict__ kAe,
    float* __restrict__ beta2)
{
  __shared__ __align__(16) float AhL[1024];
  const bool isK = blockIdx.x >= 192;
  const int rb = blockIdx.x * 256 - (isK ? 49152 : 0);
  const int h = (rb >> 10) % 12;              // uniform per block
  const int row = rb + threadIdx.x;
  const int bh = row >> 10;
  const int s = row & 1023;
  const int b_ = bh / 12;

  // stage Ah (4KB) once; uniform-address LDS reads broadcast conflict-free
  ((float4*)AhL)[threadIdx.x] = ((const float4*)(Am + h * 1024))[threadIdx.x];

  const u16* src = (isK ? Kb : Qb) + ((long)row << 6);
  union { uint4 v4[8]; u32 u[32]; } c;
  #pragma unroll
  for (int i = 0; i < 8; i++) c.v4[i] = ((const uint4*)src)[i];

  __syncthreads();

  float acc[16];
  #pragma unroll
  for (int r = 0; r < 16; r++) acc[r] = 0.f;
  float s2 = 0.f;
  #pragma unroll
  for (int d = 0; d < 64; d++) {
    u32 wd = c.u[d >> 1];
    float qd = bf2f((u16)((d & 1) ? (wd >> 16) : (wd & 0xffffu)));
    s2 += qd * qd;
    #pragma unroll
    for (int r4 = 0; r4 < 4; r4++) {
      f32x4 a4 = *(const f32x4*)&AhL[d * 16 + r4 * 4];
      acc[r4 * 4 + 0] += qd * a4[0];
      acc[r4 * 4 + 1] += qd * a4[1];
      acc[r4 * 4 + 2] += qd * a4[2];
      acc[r4 * 4 + 3] += qd * a4[3];
    }
  }

  union { u16 us[128]; uint4 v4[16]; } o;
  const float sA = isK ? 1.0f : 0.25f * LOG2E;
  const float sQ = isK ? 1e-3f : 0.25e-3f * LOG2E;
  #pragma unroll
  for (int r = 0; r < 16; r++) o.us[r] = f2bf(acc[r] * sA);
  #pragma unroll
  for (int d = 0; d < 64; d++) {
    u32 wd = c.u[d >> 1];
    float qd = bf2f((u16)((d & 1) ? (wd >> 16) : (wd & 0xffffu)));
    o.us[16 + d] = f2bf(qd * sQ);
  }
  #pragma unroll
  for (int j = 80; j < 128; j++) o.us[j] = 0;

  u16* dst = (isK ? kAe : qAe) + ((long)row << 7);
  #pragma unroll
  for (int i = 0; i < 16; i++) ((uint4*)dst)[i] = o.v4[i];

  if (isK) {
    float kk = 1e-6f * s2;
    #pragma unroll
    for (int r = 0; r < 16; r++) kk += acc[r] * acc[r];
    beta2[row] = LOG2E * (-0.125f * kk + mask[(b_ << 10) + s]);
  }
}

// ---------------- K3: attention v10 — R10 skeleton + V depth-2, single wait/iter ------
// grid 768 = 48 bh x 16 qtiles(64 rows), XCD-swizzled; block 128 = 2 waves,
// wave owns 32 q rows. 16 iterations of 64 t.
// Per iter: loadV(c+1) [reg WAR wave-private: safe pre-barrier] -> vmcnt(8)
// [K(c)+V(c) landed, V(c+1) stays in flight] -> barrier -> stage K(c+1) ->
// QK 24 MFMA -> exp/pack -> P LDS -> PV 16 MFMA with V(c) regs. ONE wait, ONE barrier.
__global__ __attribute__((amdgpu_waves_per_eu(1, 2))) __launch_bounds__(128)
void attn_kernel(
    const u16* __restrict__ qAe, const u16* __restrict__ kAe, const u16* __restrict__ Vtb,
    const float* __restrict__ beta2, u16* __restrict__ ctxb)
{
  const int tid = threadIdx.x;
  const int lane = tid & 63;
  const int w = tid >> 6;
  const int l15 = lane & 15, g = lane >> 4;
  const int wid = ((int)blockIdx.x & 7) * 96 + ((int)blockIdx.x >> 3);  // 768 = 8*96
  const int bh = wid >> 4;
  const int qt = wid & 15;
  const int q0 = qt * 64 + w * 32;

  // LDS: K dbuf 2x16384 | P 2 waves x 4608 (32 rows x 128B, stride 144) | beta 4096
  __shared__ __align__(16) char sm[46080];
  char* const kb0  = sm;
  char* const kb1  = sm + 16384;
  char* const Pw   = sm + 32768 + w * 4608;
  float* const Blds = (float*)(sm + 41984);

  const u16* qbase = qAe + ((long)(bh * 1024 + q0) << 7);
  const u16* kbase = kAe + ((long)bh << 17);
  const u16* vbase = Vtb + ((long)bh << 16);
  const float* betab = beta2 + (bh << 10);

  // prologue FIFO: [bqv 6][beta 4][K0 8][V0 8] = 26
  u32x4 bqv[2][3];
  #pragma unroll
  for (int qf = 0; qf < 2; qf++)
    #pragma unroll
    for (int ks = 0; ks < 3; ks++) {
      const u16* a = qbase + ((qf * 16 + l15) << 7) + ks * 32 + g * 8;
      asm volatile("global_load_dwordx4 %0, %1, off" : "=v"(bqv[qf][ks]) : "v"(a));
    }
  #pragma unroll
  for (int i = 0; i < 4; i++)
    gl2lds16(betab + i * 256 + lane * 4, (char*)Blds + i * 1024);   // 1024B/instr

  auto stageK = [&](int c, char* buf) {
    const int t0 = c * 64;
    #pragma unroll
    for (int i2 = 0; i2 < 8; i2++) {
      int i = w * 8 + i2;
      int r = i * 4 + (lane >> 4);
      int col = ((lane & 15) ^ (r & 7)) * 8;          // pre-swizzled source (rule #21)
      gl2lds16(kbase + (long)(t0 + r) * 128 + col, buf + i * 1024);
    }
  };
  auto loadV = [&](int c, u32x4 (&dst)[8]) {
    const int t0 = c * 64;
    #pragma unroll
    for (int ks2 = 0; ks2 < 2; ks2++)
      #pragma unroll
      for (int df = 0; df < 4; df++) {
        const u16* a = vbase + ((df * 16 + l15) << 10) + t0 + ks2 * 32 + g * 8;
        asm volatile("global_load_dwordx4 %0, %1, off" : "=v"(dst[ks2 * 4 + df]) : "v"(a));
      }
  };

  f32x4 zero = {0.f, 0.f, 0.f, 0.f};
  f32x4 cacc[2][4];
  #pragma unroll
  for (int a = 0; a < 2; a++)
    #pragma unroll
    for (int b = 0; b < 4; b++) cacc[a][b] = zero;
  float rsum[2] = {0.f, 0.f};
  u32x4 vA[8], vB[8];

  stageK(0, kb0);
  __builtin_amdgcn_sched_barrier(0);
  loadV(0, vA);

  std::integral_constant<bool, false> Ff;
  std::integral_constant<bool, true>  Tt;

  auto iter = [&](auto LASTC, int c, const char* bufc, char* bufn,
                  u32x4 (&vcur)[8], u32x4 (&vnxt)[8]) {
    constexpr bool LAST = decltype(LASTC)::value;
    if constexpr (!LAST) {
      loadV(c + 1, vnxt);                             // +8 (pre-wait: reg WAR is wave-private)
      asm volatile("s_waitcnt vmcnt(8)" ::: "memory"); // K(c)+V(c) landed; V(c+1) in flight
    } else {
      asm volatile("s_waitcnt vmcnt(0)" ::: "memory");
    }
    asm volatile("s_barrier" ::: "memory");
    __builtin_amdgcn_sched_barrier(0);                // rule #18
    if constexpr (!LAST) stageK(c + 1, bufn);         // post-barrier: WAR-safe slot
    // phase A: S^T = K @ Q^T (24 MFMA, 12 ds_read_b128 swizzled)
    f32x4 sacc[4][2];
    #pragma unroll
    for (int tf = 0; tf < 4; tf++) { sacc[tf][0] = zero; sacc[tf][1] = zero; }
    #pragma unroll
    for (int tf = 0; tf < 4; tf++)
      #pragma unroll
      for (int ks = 0; ks < 3; ks++) {
        s16x8 ak = *(const s16x8*)(bufc + (tf * 16 + l15) * 256 +
                                   ((ks * 64 + g * 16) ^ ((l15 & 7) << 4)));
        s16x8 b0 = __builtin_bit_cast(s16x8, bqv[0][ks]);
        s16x8 b1 = __builtin_bit_cast(s16x8, bqv[1][ks]);
        sacc[tf][0] = __builtin_amdgcn_mfma_f32_16x16x32_bf16(ak, b0, sacc[tf][0], 0, 0, 0);
        sacc[tf][1] = __builtin_amdgcn_mfma_f32_16x16x32_bf16(ak, b1, sacc[tf][1], 0, 0, 0);
      }
    // softmax: P = 2^(S + beta) -> bf16 -> per-wave LDS [q][t], stride 144
    #pragma unroll
    for (int tf = 0; tf < 4; tf++) {
      f32x4 bb = *(const f32x4*)((const char*)Blds + c * 256 + tf * 64 + g * 16);
      #pragma unroll
      for (int qf = 0; qf < 2; qf++) {
        float e0, e1, e2, e3;
        asm("v_exp_f32 %0, %1" : "=v"(e0) : "v"(sacc[tf][qf][0] + bb[0]));
        asm("v_exp_f32 %0, %1" : "=v"(e1) : "v"(sacc[tf][qf][1] + bb[1]));
        asm("v_exp_f32 %0, %1" : "=v"(e2) : "v"(sacc[tf][qf][2] + bb[2]));
        asm("v_exp_f32 %0, %1" : "=v"(e3) : "v"(sacc[tf][qf][3] + bb[3]));
        rsum[qf] += (e0 + e1) + (e2 + e3);
        u32 p01, p23;
        asm("v_cvt_pk_bf16_f32 %0, %1, %2" : "=v"(p01) : "v"(e0), "v"(e1));
        asm("v_cvt_pk_bf16_f32 %0, %1, %2" : "=v"(p23) : "v"(e2), "v"(e3));
        u32x2 pk = {p01, p23};
        *(u32x2*)(Pw + (qf * 16 + l15) * 144 + tf * 32 + g * 8) = pk;
      }
    }
    // phase B: ctx += P @ V (16 MFMA; P from own-wave LDS, V(c) regs — landed at top wait)
    #pragma unroll
    for (int qf = 0; qf < 2; qf++)
      #pragma unroll
      for (int ks2 = 0; ks2 < 2; ks2++) {
        s16x8 ap = *(const s16x8*)(Pw + (qf * 16 + l15) * 144 + ks2 * 64 + g * 16);
        #pragma unroll
        for (int df = 0; df < 4; df++) {
          s16x8 bv = __builtin_bit_cast(s16x8, vcur[ks2 * 4 + df]);
          cacc[qf][df] = __builtin_amdgcn_mfma_f32_16x16x32_bf16(ap, bv, cacc[qf][df], 0, 0, 0);
        }
      }
  };

  #pragma unroll 1
  for (int c2 = 0; c2 < 7; c2++) {
    iter(Ff, 2 * c2,     kb0, kb1, vA, vB);
    iter(Ff, 2 * c2 + 1, kb1, kb0, vB, vA);
  }
  iter(Ff, 14, kb0, kb1, vA, vB);
  iter(Tt, 15, kb1, kb0, vB, vA);

  // epilogue: per-wave softmax normalize + write
  #pragma unroll
  for (int qf = 0; qf < 2; qf++) {
    rsum[qf] += __shfl_xor(rsum[qf], 16);
    rsum[qf] += __shfl_xor(rsum[qf], 32);
  }
  const int b_ = bh / 12, h = bh % 12;
  #pragma unroll
  for (int qf = 0; qf < 2; qf++) {
    #pragma unroll
    for (int j = 0; j < 4; j++) {
      float rs = __shfl(rsum[qf], g * 4 + j);
      float rinv = 1.0f / rs;
      int qg = q0 + qf * 16 + g * 4 + j;
      long base = ((long)(b_ * 1024 + qg)) * 768 + h * 64;
      #pragma unroll
      for (int df = 0; df < 4; df++)
        ctxb[base + df * 16 + l15] = f2bf(cacc[qf][df][j] * rinv);
    }
  }
}

// ---------------- launcher ----------------
extern "C" void kernel_launch(void* const* d_in, const int* in_sizes, int n_in,
                              void* d_out, int out_size, void* d_ws, size_t ws_size,
                              hipStream_t stream)
{
  (void)in_sizes; (void)n_in; (void)out_size; (void)ws_size;
  const float* hs   = (const float*)d_in[0];
  const float* mask = (const float*)d_in[1];
  const float* Wq   = (const float*)d_in[2];
  const float* bq   = (const float*)d_in[3];
  const float* Wk   = (const float*)d_in[4];
  const float* bk   = (const float*)d_in[5];
  const float* Wv   = (const float*)d_in[6];
  const float* bv   = (const float*)d_in[7];
  const float* Wo   = (const float*)d_in[8];
  const float* bo   = (const float*)d_in[9];
  const float* Am   = (const float*)d_in[10];
  float* out = (float*)d_out;

  char* p = (char*)d_ws;
  u16* hsb      = (u16*)p;   p += 6291456;
  u16* wqkvb    = (u16*)p;   p += 3538944;
  u16* wob      = (u16*)p;   p += 1179648;
  float* biasqkv= (float*)p; p += 9216;
  u16* Qb       = (u16*)p;   p += 6291456;
  u16* Kb       = (u16*)p;   p += 6291456;
  u16* Vtb      = (u16*)p;   p += 6291456;
  u16* qAeb     = (u16*)p;   p += 12582912;
  u16* kAeb     = (u16*)p;   p += 12582912;
  float* beta2  = (float*)p; p += 196608;
  u16* ctxb     = (u16*)p;   p += 6291456;

  convert_kernel<<<2688, 256, 0, stream>>>(hs, Wq, Wk, Wv, Wo, bq, bk, bv,
                                           hsb, wqkvb, wob, biasqkv);
  gemm_bt<0><<<1152, 256, 0, stream>>>(hsb, wqkvb, biasqkv,
                                       nullptr, Qb, Kb, Vtb);
  qk_ext_kernel<<<384, 256, 0, stream>>>(Qb, Kb, Am, mask, qAeb, kAeb, beta2);
  attn_kernel<<<768, 128, 0, stream>>>(qAeb, kAeb, Vtb, beta2, ctxb);
  gemm_bt<1><<<384, 256, 0, stream>>>(ctxb, wob, bo, out,
                                      nullptr, nullptr, nullptr);
}

// Round 14
// 95.135 us; speedup vs baseline: 1.1495x; 1.1307x over previous
//
#include <hip/hip_runtime.h>

typedef __attribute__((ext_vector_type(8))) short s16x8;
typedef __attribute__((ext_vector_type(4))) float f32x4;
typedef __attribute__((ext_vector_type(4))) unsigned int u32x4;
typedef __attribute__((ext_vector_type(2))) unsigned int u32x2;
typedef unsigned short u16;
typedef unsigned int u32;
typedef unsigned long long u64;

__device__ __forceinline__ u16 f2bf(float f) {
  u32 u = __float_as_uint(f);
  u32 r = u + 0x7fffu + ((u >> 16) & 1u);
  return (u16)(r >> 16);
}
__device__ __forceinline__ float bf2f(u16 h) {
  return __uint_as_float(((u32)h) << 16);
}

typedef __attribute__((address_space(3))) char lds_char_t;
typedef __attribute__((address_space(1))) const char glb_char_t;
__device__ __forceinline__ void gl2lds16(const void* g, void* l) {
  __builtin_amdgcn_global_load_lds((glb_char_t*)g, (lds_char_t*)l, 16, 0, 0);
}

#define HS_N 3145728   // 4096*768
#define W_N  589824    // 768*768
#define LOG2E 1.44269504f

// ---------------- K0: f32 -> bf16 conversions + bias concat ----------------
__global__ __launch_bounds__(256) void convert_kernel(
    const float* __restrict__ hs, const float* __restrict__ wq, const float* __restrict__ wk,
    const float* __restrict__ wv, const float* __restrict__ wo,
    const float* __restrict__ bq, const float* __restrict__ bk, const float* __restrict__ bv,
    u16* __restrict__ hsb, u16* __restrict__ wqkvb, u16* __restrict__ wob,
    float* __restrict__ biasqkv)
{
  int t = blockIdx.x * 256 + threadIdx.x;
  long i = (long)t * 8;
  const float* src;
  u16* dst;
  if (i < HS_N)              { src = hs + i;                  dst = hsb + i; }
  else if (i < HS_N + W_N)   { src = wq + (i - HS_N);         dst = wqkvb + (i - HS_N); }
  else if (i < HS_N + 2*W_N) { src = wk + (i - HS_N - W_N);   dst = wqkvb + (i - HS_N); }
  else if (i < HS_N + 3*W_N) { src = wv + (i - HS_N - 2*W_N); dst = wqkvb + (i - HS_N); }
  else                       { src = wo + (i - HS_N - 3*W_N); dst = wob + (i - HS_N - 3*W_N); }
  float4 a = ((const float4*)src)[0];
  float4 b = ((const float4*)src)[1];
  uint4 o;
  o.x = (u32)f2bf(a.x) | ((u32)f2bf(a.y) << 16);
  o.y = (u32)f2bf(a.z) | ((u32)f2bf(a.w) << 16);
  o.z = (u32)f2bf(b.x) | ((u32)f2bf(b.y) << 16);
  o.w = (u32)f2bf(b.z) | ((u32)f2bf(b.w) << 16);
  *(uint4*)dst = o;
  if (t < 2304) biasqkv[t] = (t < 768) ? bq[t] : ((t < 1536) ? bk[t - 768] : bv[t - 1536]);
}

// ---------------- GEMM v2 (R4-exact): async-pipelined, C = A @ Bt^T + bias ----
template<int MODE>
__global__ __launch_bounds__(256, 2) void gemm_bt(
    const u16* __restrict__ A, const u16* __restrict__ Bt, const float* __restrict__ bias,
    float* __restrict__ outF, u16* __restrict__ Qb, u16* __restrict__ Kb, u16* __restrict__ Vtb)
{
  constexpr int NT = (MODE == 0) ? 18 : 6;
  constexpr int CPX = NT * 64 / 8;

  __shared__ __align__(16) char sm[73728];
  char* const smA = sm;
  char* const smB = sm + 24576;

  const int tid = threadIdx.x;
  const int lane = tid & 63;
  const int w = tid >> 6;
  const int l15 = lane & 15, g = lane >> 4;
  const int wid = (blockIdx.x & 7) * CPX + (blockIdx.x >> 3);
  const int bx = wid % NT, by = wid / NT;
  const int mBase = by * 64;
  const int nBase = bx * 128;
  const int wr = w >> 1, wc = w & 1;
  const int mW = wr * 32, nW = wc * 64;

  f32x4 zero = {0.f, 0.f, 0.f, 0.f};
  f32x4 acc[2][4];
  #pragma unroll
  for (int i = 0; i < 2; i++)
    #pragma unroll
    for (int j = 0; j < 4; j++) acc[i][j] = zero;

  const u16* Arow = A + (long)mBase * 768;
  const u16* Brow = Bt + (long)nBase * 768;

  auto stage = [&](int c, int kb) {
    const int k0 = c * 64;
    #pragma unroll
    for (int i = 0; i < 2; i++) {
      int o = (i * 256 + tid) * 16;
      int r = o >> 7;
      int sl = ((o >> 4) & 7) ^ (r & 7);
      gl2lds16(Arow + (long)r * 768 + k0 + sl * 8,
               smA + kb * 8192 + i * 4096 + w * 1024);
    }
    #pragma unroll
    for (int i = 0; i < 4; i++) {
      int o = (i * 256 + tid) * 16;
      int r = o >> 7;
      int sl = ((o >> 4) & 7) ^ (r & 7);
      gl2lds16(Brow + (long)r * 768 + k0 + sl * 8,
               smB + kb * 16384 + i * 4096 + w * 1024);
    }
  };

  auto compute = [&](int kb) {
    const char* bufA = smA + kb * 8192;
    const char* bufB = smB + kb * 16384;
    #pragma unroll
    for (int kh = 0; kh < 2; kh++) {
      s16x8 af[2], bf[4];
      #pragma unroll
      for (int mi = 0; mi < 2; mi++) {
        int R = mW + mi * 16 + l15;
        af[mi] = *(const s16x8*)(bufA + R * 128 + (((kh * 4 + g) ^ (l15 & 7)) << 4));
      }
      #pragma unroll
      for (int ni = 0; ni < 4; ni++) {
        int R = nW + ni * 16 + l15;
        bf[ni] = *(const s16x8*)(bufB + R * 128 + (((kh * 4 + g) ^ (l15 & 7)) << 4));
      }
      #pragma unroll
      for (int mi = 0; mi < 2; mi++)
        #pragma unroll
        for (int ni = 0; ni < 4; ni++)
          acc[mi][ni] = __builtin_amdgcn_mfma_f32_16x16x32_bf16(af[mi], bf[ni], acc[mi][ni], 0, 0, 0);
    }
  };

  auto body = [&](int c, int kb, int kbn) {
    if (c < 11) { stage(c + 1, kbn); asm volatile("s_waitcnt vmcnt(6)" ::: "memory"); }
    else        { asm volatile("s_waitcnt vmcnt(0)" ::: "memory"); }
    asm volatile("s_barrier" ::: "memory");
    compute(kb);
  };

  stage(0, 0);
  #pragma unroll 1
  for (int cc = 0; cc < 4; cc++) {
    body(cc * 3,     0, 1);
    body(cc * 3 + 1, 1, 2);
    body(cc * 3 + 2, 2, 0);
  }
  __syncthreads();

  const int b_ = mBase >> 10;
  const int s0b = mBase & 1023;

  if constexpr (MODE == 1) {
    #pragma unroll
    for (int mi = 0; mi < 2; mi++)
      #pragma unroll
      for (int ni = 0; ni < 4; ni++) {
        int n = nBase + nW + ni * 16 + l15;
        int m0 = mBase + mW + mi * 16 + g * 4;
        float bb = bias[n];
        outF[(long)m0 * 768 + n]       = acc[mi][ni][0] + bb;
        outF[(long)(m0 + 1) * 768 + n] = acc[mi][ni][1] + bb;
        outF[(long)(m0 + 2) * 768 + n] = acc[mi][ni][2] + bb;
        outF[(long)(m0 + 3) * 768 + n] = acc[mi][ni][3] + bb;
      }
  } else {
    const int typ = bx / 6;
    if (typ < 2) {
      u16* qk = (typ == 0) ? Qb : Kb;
      #pragma unroll
      for (int mi = 0; mi < 2; mi++)
        #pragma unroll
        for (int ni = 0; ni < 4; ni++) {
          int n = nBase + nW + ni * 16 + l15;
          int hn = n - typ * 768;
          int h = hn >> 6, d = hn & 63;
          long bh = (long)b_ * 12 + h;
          int s0 = s0b + mW + mi * 16 + g * 4;
          float bb = bias[n];
          u16* dst = qk + (bh << 16) + ((long)s0 << 6) + d;
          dst[0]   = f2bf(acc[mi][ni][0] + bb);
          dst[64]  = f2bf(acc[mi][ni][1] + bb);
          dst[128] = f2bf(acc[mi][ni][2] + bb);
          dst[192] = f2bf(acc[mi][ni][3] + bb);
        }
    } else {
      u16* ct = (u16*)sm;
      #pragma unroll
      for (int mi = 0; mi < 2; mi++)
        #pragma unroll
        for (int ni = 0; ni < 4; ni++) {
          int nr = nW + ni * 16 + l15;
          int mr = mW + mi * 16 + g * 4;
          float bb = bias[nBase + nr];
          u32 lo = (u32)f2bf(acc[mi][ni][0] + bb) | ((u32)f2bf(acc[mi][ni][1] + bb) << 16);
          u32 hi = (u32)f2bf(acc[mi][ni][2] + bb) | ((u32)f2bf(acc[mi][ni][3] + bb) << 16);
          *(u64*)(ct + nr * 72 + mr) = (u64)lo | ((u64)hi << 32);
        }
      __syncthreads();
      int dr = tid >> 1, part = tid & 1;
      int hn = (bx - 12) * 128 + dr;
      int h = hn >> 6, d = hn & 63;
      long bh = (long)b_ * 12 + h;
      u16* dst = Vtb + (bh << 16) + (d << 10) + s0b + part * 32;
      const u16* srl = ct + dr * 72 + part * 32;
      #pragma unroll
      for (int i = 0; i < 4; i++)
        *(uint4*)(dst + i * 8) = *(const uint4*)(srl + i * 8);
    }
  }
}

// ---------------- K2 (R13): extended features + beta, LOG2E folded; Ah staged in LDS ---
__global__ __launch_bounds__(256) void qk_ext_kernel(
    const u16* __restrict__ Qb, const u16* __restrict__ Kb, const float* __restrict__ Am,
    const float* __restrict__ mask, u16* __restrict__ qAe, u16* __restrict__ kAe,
    float* __restrict__ beta2)
{
  __shared__ __align__(16) float AhL[1024];
  const bool isK = blockIdx.x >= 192;
  const int rb = blockIdx.x * 256 - (isK ? 49152 : 0);
  const int h = (rb >> 10) % 12;              // uniform per block
  const int row = rb + threadIdx.x;
  const int bh = row >> 10;
  const int s = row & 1023;
  const int b_ = bh / 12;

  // stage Ah (4KB) once; uniform-address LDS reads broadcast conflict-free
  ((float4*)AhL)[threadIdx.x] = ((const float4*)(Am + h * 1024))[threadIdx.x];

  const u16* src = (isK ? Kb : Qb) + ((long)row << 6);
  union { uint4 v4[8]; u32 u[32]; } c;
  #pragma unroll
  for (int i = 0; i < 8; i++) c.v4[i] = ((const uint4*)src)[i];

  __syncthreads();

  float acc[16];
  #pragma unroll
  for (int r = 0; r < 16; r++) acc[r] = 0.f;
  float s2 = 0.f;
  #pragma unroll
  for (int d = 0; d < 64; d++) {
    u32 wd = c.u[d >> 1];
    float qd = bf2f((u16)((d & 1) ? (wd >> 16) : (wd & 0xffffu)));
    s2 += qd * qd;
    #pragma unroll
    for (int r4 = 0; r4 < 4; r4++) {
      f32x4 a4 = *(const f32x4*)&AhL[d * 16 + r4 * 4];
      acc[r4 * 4 + 0] += qd * a4[0];
      acc[r4 * 4 + 1] += qd * a4[1];
      acc[r4 * 4 + 2] += qd * a4[2];
      acc[r4 * 4 + 3] += qd * a4[3];
    }
  }

  union { u16 us[128]; uint4 v4[16]; } o;
  const float sA = isK ? 1.0f : 0.25f * LOG2E;
  const float sQ = isK ? 1e-3f : 0.25e-3f * LOG2E;
  #pragma unroll
  for (int r = 0; r < 16; r++) o.us[r] = f2bf(acc[r] * sA);
  #pragma unroll
  for (int d = 0; d < 64; d++) {
    u32 wd = c.u[d >> 1];
    float qd = bf2f((u16)((d & 1) ? (wd >> 16) : (wd & 0xffffu)));
    o.us[16 + d] = f2bf(qd * sQ);
  }
  #pragma unroll
  for (int j = 80; j < 128; j++) o.us[j] = 0;

  u16* dst = (isK ? kAe : qAe) + ((long)row << 7);
  #pragma unroll
  for (int i = 0; i < 16; i++) ((uint4*)dst)[i] = o.v4[i];

  if (isK) {
    float kk = 1e-6f * s2;
    #pragma unroll
    for (int r = 0; r < 16; r++) kk += acc[r] * acc[r];
    beta2[row] = LOG2E * (-0.125f * kk + mask[(b_ << 10) + s]);
  }
}

// ---------------- K3: attention (R10-exact, best measured: 43 us) ----------------
// grid 768 = 48 bh x 16 qtiles(64 rows), XCD-swizzled; block 128 = 2 waves,
// wave owns 32 q rows. 16 iterations of 64 t each.
// Per iter: loadV(c) 8 -> wait vmcnt(8) [K(c) landed] -> barrier ->
//           stage K(c+1) 8 -> QK 24 MFMA -> wait vmcnt(8) [V(c) landed] ->
//           exp+pack -> P LDS -> PV 16 MFMA.
__global__ __launch_bounds__(128, 2) void attn_kernel(
    const u16* __restrict__ qAe, const u16* __restrict__ kAe, const u16* __restrict__ Vtb,
    const float* __restrict__ beta2, u16* __restrict__ ctxb)
{
  const int tid = threadIdx.x;
  const int lane = tid & 63;
  const int w = tid >> 6;
  const int l15 = lane & 15, g = lane >> 4;
  const int wid = ((int)blockIdx.x & 7) * 96 + ((int)blockIdx.x >> 3);  // 768 = 8*96
  const int bh = wid >> 4;
  const int qt = wid & 15;
  const int q0 = qt * 64 + w * 32;

  // LDS: K dbuf 2x16384 | P 2 waves x 4608 (32 rows x 128B, stride 144) | beta 4096
  __shared__ __align__(16) char sm[46080];
  char* const kb0  = sm;
  char* const kb1  = sm + 16384;
  char* const Pw   = sm + 32768 + w * 4608;
  float* const Blds = (float*)(sm + 41984);

  const u16* qbase = qAe + ((long)(bh * 1024 + q0) << 7);
  const u16* kbase = kAe + ((long)bh << 17);
  const u16* vbase = Vtb + ((long)bh << 16);
  const float* betab = beta2 + (bh << 10);

  // prologue FIFO: [bqv 6][beta 4][K0 8] = 18
  u32x4 bqv[2][3];
  #pragma unroll
  for (int qf = 0; qf < 2; qf++)
    #pragma unroll
    for (int ks = 0; ks < 3; ks++) {
      const u16* a = qbase + ((qf * 16 + l15) << 7) + ks * 32 + g * 8;
      asm volatile("global_load_dwordx4 %0, %1, off" : "=v"(bqv[qf][ks]) : "v"(a));
    }
  #pragma unroll
  for (int i = 0; i < 4; i++)
    gl2lds16(betab + i * 256 + lane * 4, (char*)Blds + i * 1024);   // 1024B/instr

  auto stageK = [&](int c, char* buf) {
    const int t0 = c * 64;
    #pragma unroll
    for (int i2 = 0; i2 < 8; i2++) {
      int i = w * 8 + i2;
      int r = i * 4 + (lane >> 4);
      int col = ((lane & 15) ^ (r & 7)) * 8;          // pre-swizzled source (rule #21)
      gl2lds16(kbase + (long)(t0 + r) * 128 + col, buf + i * 1024);
    }
  };
  auto loadV = [&](int c, u32x4 (&dst)[8]) {
    const int t0 = c * 64;
    #pragma unroll
    for (int ks2 = 0; ks2 < 2; ks2++)
      #pragma unroll
      for (int df = 0; df < 4; df++) {
        const u16* a = vbase + ((df * 16 + l15) << 10) + t0 + ks2 * 32 + g * 8;
        asm volatile("global_load_dwordx4 %0, %1, off" : "=v"(dst[ks2 * 4 + df]) : "v"(a));
      }
  };

  f32x4 zero = {0.f, 0.f, 0.f, 0.f};
  f32x4 cacc[2][4];
  #pragma unroll
  for (int a = 0; a < 2; a++)
    #pragma unroll
    for (int b = 0; b < 4; b++) cacc[a][b] = zero;
  float rsum[2] = {0.f, 0.f};
  u32x4 vb[8];

  stageK(0, kb0);

  std::integral_constant<bool, false> Ff;
  std::integral_constant<bool, true>  Tt;

  auto iter = [&](auto LASTC, int c, const char* bufc, char* bufn) {
    constexpr bool LAST = decltype(LASTC)::value;
    loadV(c, vb);                                   // +8
    asm volatile("s_waitcnt vmcnt(8)" ::: "memory"); // K(c) landed (V(c) remains)
    asm volatile("s_barrier" ::: "memory");
    __builtin_amdgcn_sched_barrier(0);
    if constexpr (!LAST) stageK(c + 1, bufn);       // post-barrier: WAR-safe slot
    // phase A: S^T = K @ Q^T (24 MFMA, 12 ds_read_b128 swizzled)
    f32x4 sacc[4][2];
    #pragma unroll
    for (int tf = 0; tf < 4; tf++) { sacc[tf][0] = zero; sacc[tf][1] = zero; }
    #pragma unroll
    for (int tf = 0; tf < 4; tf++)
      #pragma unroll
      for (int ks = 0; ks < 3; ks++) {
        s16x8 ak = *(const s16x8*)(bufc + (tf * 16 + l15) * 256 +
                                   ((ks * 64 + g * 16) ^ ((l15 & 7) << 4)));
        s16x8 b0 = __builtin_bit_cast(s16x8, bqv[0][ks]);
        s16x8 b1 = __builtin_bit_cast(s16x8, bqv[1][ks]);
        sacc[tf][0] = __builtin_amdgcn_mfma_f32_16x16x32_bf16(ak, b0, sacc[tf][0], 0, 0, 0);
        sacc[tf][1] = __builtin_amdgcn_mfma_f32_16x16x32_bf16(ak, b1, sacc[tf][1], 0, 0, 0);
      }
    if constexpr (!LAST) asm volatile("s_waitcnt vmcnt(8)" ::: "memory");  // V(c) landed
    else                 asm volatile("s_waitcnt vmcnt(0)" ::: "memory");
    __builtin_amdgcn_sched_barrier(0);              // rule #18
    // softmax: P = 2^(S + beta) -> bf16 -> per-wave LDS [q][t], stride 144
    #pragma unroll
    for (int tf = 0; tf < 4; tf++) {
      f32x4 bb = *(const f32x4*)((const char*)Blds + c * 256 + tf * 64 + g * 16);
      #pragma unroll
      for (int qf = 0; qf < 2; qf++) {
        float e0, e1, e2, e3;
        asm("v_exp_f32 %0, %1" : "=v"(e0) : "v"(sacc[tf][qf][0] + bb[0]));
        asm("v_exp_f32 %0, %1" : "=v"(e1) : "v"(sacc[tf][qf][1] + bb[1]));
        asm("v_exp_f32 %0, %1" : "=v"(e2) : "v"(sacc[tf][qf][2] + bb[2]));
        asm("v_exp_f32 %0, %1" : "=v"(e3) : "v"(sacc[tf][qf][3] + bb[3]));
        rsum[qf] += (e0 + e1) + (e2 + e3);
        u32 p01, p23;
        asm("v_cvt_pk_bf16_f32 %0, %1, %2" : "=v"(p01) : "v"(e0), "v"(e1));
        asm("v_cvt_pk_bf16_f32 %0, %1, %2" : "=v"(p23) : "v"(e2), "v"(e3));
        u32x2 pk = {p01, p23};
        *(u32x2*)(Pw + (qf * 16 + l15) * 144 + tf * 32 + g * 8) = pk;
      }
    }
    // phase B: ctx += P @ V (16 MFMA; P from own-wave LDS, V in regs)
    #pragma unroll
    for (int qf = 0; qf < 2; qf++)
      #pragma unroll
      for (int ks2 = 0; ks2 < 2; ks2++) {
        s16x8 ap = *(const s16x8*)(Pw + (qf * 16 + l15) * 144 + ks2 * 64 + g * 16);
        #pragma unroll
        for (int df = 0; df < 4; df++) {
          s16x8 bv = __builtin_bit_cast(s16x8, vb[ks2 * 4 + df]);
          cacc[qf][df] = __builtin_amdgcn_mfma_f32_16x16x32_bf16(ap, bv, cacc[qf][df], 0, 0, 0);
        }
      }
  };

  #pragma unroll 1
  for (int c2 = 0; c2 < 7; c2++) {
    iter(Ff, 2 * c2,     kb0, kb1);
    iter(Ff, 2 * c2 + 1, kb1, kb0);
  }
  iter(Ff, 14, kb0, kb1);
  iter(Tt, 15, kb1, kb0);

  // epilogue: per-wave softmax normalize + write
  #pragma unroll
  for (int qf = 0; qf < 2; qf++) {
    rsum[qf] += __shfl_xor(rsum[qf], 16);
    rsum[qf] += __shfl_xor(rsum[qf], 32);
  }
  const int b_ = bh / 12, h = bh % 12;
  #pragma unroll
  for (int qf = 0; qf < 2; qf++) {
    #pragma unroll
    for (int j = 0; j < 4; j++) {
      float rs = __shfl(rsum[qf], g * 4 + j);
      float rinv = 1.0f / rs;
      int qg = q0 + qf * 16 + g * 4 + j;
      long base = ((long)(b_ * 1024 + qg)) * 768 + h * 64;
      #pragma unroll
      for (int df = 0; df < 4; df++)
        ctxb[base + df * 16 + l15] = f2bf(cacc[qf][df][j] * rinv);
    }
  }
}

// ---------------- launcher ----------------
extern "C" void kernel_launch(void* const* d_in, const int* in_sizes, int n_in,
                              void* d_out, int out_size, void* d_ws, size_t ws_size,
                              hipStream_t stream)
{
  (void)in_sizes; (void)n_in; (void)out_size; (void)ws_size;
  const float* hs   = (const float*)d_in[0];
  const float* mask = (const float*)d_in[1];
  const float* Wq   = (const float*)d_in[2];
  const float* bq   = (const float*)d_in[3];
  const float* Wk   = (const float*)d_in[4];
  const float* bk   = (const float*)d_in[5];
  const float* Wv   = (const float*)d_in[6];
  const float* bv   = (const float*)d_in[7];
  const float* Wo   = (const float*)d_in[8];
  const float* bo   = (const float*)d_in[9];
  const float* Am   = (const float*)d_in[10];
  float* out = (float*)d_out;

  char* p = (char*)d_ws;
  u16* hsb      = (u16*)p;   p += 6291456;
  u16* wqkvb    = (u16*)p;   p += 3538944;
  u16* wob      = (u16*)p;   p += 1179648;
  float* biasqkv= (float*)p; p += 9216;
  u16* Qb       = (u16*)p;   p += 6291456;
  u16* Kb       = (u16*)p;   p += 6291456;
  u16* Vtb      = (u16*)p;   p += 6291456;
  u16* qAeb     = (u16*)p;   p += 12582912;
  u16* kAeb     = (u16*)p;   p += 12582912;
  float* beta2  = (float*)p; p += 196608;
  u16* ctxb     = (u16*)p;   p += 6291456;

  convert_kernel<<<2688, 256, 0, stream>>>(hs, Wq, Wk, Wv, Wo, bq, bk, bv,
                                           hsb, wqkvb, wob, biasqkv);
  gemm_bt<0><<<1152, 256, 0, stream>>>(hsb, wqkvb, biasqkv,
                                       nullptr, Qb, Kb, Vtb);
  qk_ext_kernel<<<384, 256, 0, stream>>>(Qb, Kb, Am, mask, qAeb, kAeb, beta2);
  attn_kernel<<<768, 128, 0, stream>>>(qAeb, kAeb, Vtb, beta2, ctxb);
  gemm_bt<1><<<384, 256, 0, stream>>>(ctxb, wob, bo, out,
                                      nullptr, nullptr, nullptr);
}